// Round 14
// baseline (511.808 us; speedup 1.0000x reference)
//
#include <hip/hip_runtime.h>
#include <hip/hip_bf16.h>
#include <math.h>

#define NROWS 16384
#define HID 64
#define KSPLIT 8
#define KCH (NROWS / KSPLIT)  // 2048
#define NSTAGE 32             // 2 k-steps (64 k) per stage

typedef __attribute__((ext_vector_type(8))) __bf16 bf16x8;
typedef __attribute__((ext_vector_type(4))) float f32x4;

__device__ inline f32x4 mfma16(bf16x8 a, bf16x8 b, f32x4 c) {
    return __builtin_amdgcn_mfma_f32_16x16x32_bf16(a, b, c, 0, 0, 0);
}

__device__ inline void split8v(const f32x4 v0, const f32x4 v1, bf16x8& h, bf16x8& l) {
    float f[8] = {v0[0], v0[1], v0[2], v0[3], v1[0], v1[1], v1[2], v1[3]};
#pragma unroll
    for (int j = 0; j < 8; ++j) {
        __bf16 hh = (__bf16)f[j];
        h[j] = hh;
        l[j] = (__bf16)(f[j] - (float)hh);
    }
}

// ---------------------------------------------------------------------------
// pack_b: x [16384,64] fp32 row-major  ->  MFMA B-fragment-ordered bf16 hi/lo.
// ---------------------------------------------------------------------------
__global__ __launch_bounds__(256) void pack_b(const float* __restrict__ x,
                                              __bf16* __restrict__ hi,
                                              __bf16* __restrict__ lo) {
    __shared__ float tile[32 * 64];
    const int kb = blockIdx.x;  // 0..511, 32 k-rows each
    const f32x4* src = (const f32x4*)(x + (size_t)kb * 32 * 64);
    f32x4* dst = (f32x4*)tile;
    dst[threadIdx.x] = src[threadIdx.x];
    dst[threadIdx.x + 256] = src[threadIdx.x + 256];
    __syncthreads();
    const int t = threadIdx.x >> 6;    // n-tile 0..3
    const int l = threadIdx.x & 63;    // consumer lane
    const int col = (t << 4) + (l & 15);
    const int krow = (l >> 4) * 8;
    bf16x8 h8, l8;
#pragma unroll
    for (int j = 0; j < 8; ++j) {
        float v = tile[(krow + j) * 64 + col];
        __bf16 hh = (__bf16)v;
        h8[j] = hh;
        l8[j] = (__bf16)(v - (float)hh);
    }
    const size_t base = (((size_t)kb * 4 + t) * 64 + l) * 8;
    *(bf16x8*)(hi + base) = h8;
    *(bf16x8*)(lo + base) = l8;
}

// ---------------------------------------------------------------------------
// gemm_partial: partial[ks] = adj[:, ks-chunk] @ x[ks-chunk, :]
// r13 (499us, B:A VMEM 1:1, 5.1 TB/s) + LDS-STAGED B: the remaining B VMEM
// traffic was 4-way redundant across the block's waves. Now each wave
// global-loads 1/4 of each stage's B bytes (4 instr/stage), ds_writes to a
// double-buffered 2x16KB LDS region, and all waves ds_read fragments (LDS
// pipe, not VMEM). Per-CU VMEM mix per stage: 16 A-instr vs 4 B-instr (20%),
// down from 50% -- r12 probe interpolation predicts ~5.7 TB/s A delivery.
// Stage = 2 k-steps (96 MFMA between barriers). T14: B-loads for stage s+1
// issued before consuming s; ds_write after; one __syncthreads per stage.
// Block = 4 waves x 64 rows (G=4, r13's winning shape); grid ks*64+rt.
// adj loads plain; partial stores nt.
// ---------------------------------------------------------------------------
__global__ __launch_bounds__(256, 2) void gemm_partial(const float* __restrict__ adj,
                                                       const __bf16* __restrict__ Bhi,
                                                       const __bf16* __restrict__ Blo,
                                                       float* __restrict__ partial) {
    __shared__ char bsm[2][16384];  // [buf][ hi(2 steps x 4KB) | lo(2 steps x 4KB) ]

    const int tid = threadIdx.x;
    const int lane = tid & 63;
    const int wv = tid >> 6;           // wave -> 64-row group; also B-stager 1/4
    const int rt = blockIdx.x & 63;    // row-tile 0..63 (256 rows each)
    const int ks = blockIdx.x >> 6;    // k-split 0..7
    const int rbase = rt * 256 + wv * 64;
    const int rq = lane & 15;          // A row within 16-row group
    const int kq = lane >> 4;          // k-quarter 0..3

    f32x4 acc[4][4];
#pragma unroll
    for (int g = 0; g < 4; ++g)
#pragma unroll
        for (int t = 0; t < 4; ++t) acc[g][t] = f32x4{0.f, 0.f, 0.f, 0.f};

    const float* ap = adj + (size_t)(rbase + rq) * NROWS + ks * KCH + kq * 8;
    const __bf16* bhc = Bhi + (size_t)(ks * 64) * 2048;  // this chunk's hi base
    const __bf16* blc = Blo + (size_t)(ks * 64) * 2048;

    // stager instruction i = wv*4+j covers: half=i>>3 (hi/lo), sstep=(i>>2)&1,
    // quarter=i&3 (512-elem slice); per-lane 16B.
    bf16x8 breg[4];
#define LOADSTAGE(st)                                                          \
    {                                                                          \
        _Pragma("unroll") for (int j = 0; j < 4; ++j) {                        \
            const int i = wv * 4 + j;                                          \
            const __bf16* src = ((i >> 3) ? blc : bhc) +                       \
                                (size_t)(2 * (st) + ((i >> 2) & 1)) * 2048 +   \
                                (i & 3) * 512 + lane * 8;                      \
            breg[j] = *(const bf16x8*)src;                                     \
        }                                                                      \
    }
#define WRITESTAGE(buf)                                                        \
    {                                                                          \
        _Pragma("unroll") for (int j = 0; j < 4; ++j) {                        \
            const int i = wv * 4 + j;                                          \
            char* dst = bsm[buf] + (i >> 3) * 8192 + ((i >> 2) & 1) * 4096 +   \
                        (i & 3) * 1024 + lane * 16;                            \
            *(bf16x8*)dst = breg[j];                                           \
        }                                                                      \
    }

    LOADSTAGE(0);
    WRITESTAGE(0);
    __syncthreads();

    for (int st = 0; st < NSTAGE; ++st) {
        const int buf = st & 1;
        if (st + 1 < NSTAGE) LOADSTAGE(st + 1);  // issue early; consume late

        // A batch for both steps of this stage: 16 loads, issued up front
        f32x4 av[2][4][2];
#pragma unroll
        for (int ss = 0; ss < 2; ++ss)
#pragma unroll
            for (int g = 0; g < 4; ++g) {
                const f32x4* a = (const f32x4*)(ap + (size_t)(g * 16) * NROWS +
                                                (2 * st + ss) * 32);
                av[ss][g][0] = a[0];
                av[ss][g][1] = a[1];
            }

#pragma unroll
        for (int ss = 0; ss < 2; ++ss) {
            const char* hib = bsm[buf] + ss * 4096 + lane * 16;
            bf16x8 bh[4], bl[4];
#pragma unroll
            for (int t = 0; t < 4; ++t) {
                bh[t] = *(const bf16x8*)(hib + t * 1024);
                bl[t] = *(const bf16x8*)(hib + 8192 + t * 1024);
            }
#pragma unroll
            for (int g = 0; g < 4; ++g) {
                bf16x8 ah, al;
                split8v(av[ss][g][0], av[ss][g][1], ah, al);
#pragma unroll
                for (int t = 0; t < 4; ++t) {
                    acc[g][t] = mfma16(ah, bh[t], acc[g][t]);
                    acc[g][t] = mfma16(ah, bl[t], acc[g][t]);
                    acc[g][t] = mfma16(al, bh[t], acc[g][t]);
                }
            }
        }

        if (st + 1 < NSTAGE) WRITESTAGE(buf ^ 1);  // late write into other buf
        __syncthreads();
    }

    // C/D layout: col = lane&15, row = (lane>>4)*4 + reg   [m89-verified]
    float* pp = partial + (size_t)ks * (NROWS * HID) + (size_t)rbase * HID;
#pragma unroll
    for (int g = 0; g < 4; ++g)
#pragma unroll
        for (int t = 0; t < 4; ++t)
#pragma unroll
            for (int r = 0; r < 4; ++r)
                __builtin_nontemporal_store(acc[g][t][r],
                    pp + (g * 16 + kq * 4 + r) * HID + t * 16 + rq);
}

// ---------------------------------------------------------------------------
// reduce_dense: agg_r = sum_ks partial[ks][r]; x_out[r] = tanh([agg_r|x_r] @ W)
// ---------------------------------------------------------------------------
__global__ __launch_bounds__(256) void reduce_dense(const float* __restrict__ partial,
                                                    const float* __restrict__ xin,
                                                    const float* __restrict__ W,
                                                    float* __restrict__ xout) {
    __shared__ float wsm[128 * 64];  // 32 KB
    const f32x4* wsrc = (const f32x4*)W;
    f32x4* wdst = (f32x4*)wsm;
#pragma unroll
    for (int i = 0; i < 8; ++i) wdst[threadIdx.x + 256 * i] = wsrc[threadIdx.x + 256 * i];
    __syncthreads();

    const int lane = threadIdx.x & 63;
    const int wv = threadIdx.x >> 6;
    const int r0 = blockIdx.x * 32 + wv * 8;
#pragma unroll 2
    for (int i = 0; i < 8; ++i) {
        const int r = r0 + i;
        float av = 0.f;
#pragma unroll
        for (int ks = 0; ks < KSPLIT; ++ks)
            av += partial[(size_t)ks * (NROWS * HID) + (size_t)r * HID + lane];
        const float xv = xin[(size_t)r * HID + lane];
        float z = 0.f;
#pragma unroll
        for (int j = 0; j < 64; ++j) z += __shfl(av, j) * wsm[j * 64 + lane];
#pragma unroll
        for (int j = 0; j < 64; ++j) z += __shfl(xv, j) * wsm[(64 + j) * 64 + lane];
        xout[(size_t)r * HID + lane] = tanhf(z);
    }
}

extern "C" void kernel_launch(void* const* d_in, const int* in_sizes, int n_in,
                              void* d_out, int out_size, void* d_ws, size_t ws_size,
                              hipStream_t stream) {
    const float* x0 = (const float*)d_in[0];   // user_embs [16384,64]
    const float* adj = (const float*)d_in[1];  // adj [16384,16384]
    const float* W = (const float*)d_in[2];    // W [2,128,64]
    float* out = (float*)d_out;

    char* ws = (char*)d_ws;
    __bf16* Bhi = (__bf16*)(ws);                       // 2 MB
    __bf16* Blo = (__bf16*)(ws + (2u << 20));          // 2 MB
    float* partial = (float*)(ws + (4u << 20));        // 32 MB (8 x 4 MB)
    float* x1 = (float*)(ws + (36u << 20));            // 4 MB

    // hop 0
    pack_b<<<512, 256, 0, stream>>>(x0, Bhi, Blo);
    gemm_partial<<<KSPLIT * 64, 256, 0, stream>>>(adj, Bhi, Blo, partial);
    reduce_dense<<<512, 256, 0, stream>>>(partial, x0, W, x1);
    // hop 1
    pack_b<<<512, 256, 0, stream>>>(x1, Bhi, Blo);
    gemm_partial<<<KSPLIT * 64, 256, 0, stream>>>(adj, Bhi, Blo, partial);
    reduce_dense<<<512, 256, 0, stream>>>(partial, x1, W + 128 * 64, out);
}

// Round 15
// 453.703 us; speedup vs baseline: 1.1281x; 1.1281x over previous
//
#include <hip/hip_runtime.h>
#include <hip/hip_bf16.h>
#include <math.h>

#define NROWS 16384
#define HID 64
#define KSPLIT 8
#define KCH (NROWS / KSPLIT)  // 2048

typedef __attribute__((ext_vector_type(8))) __bf16 bf16x8;
typedef __attribute__((ext_vector_type(4))) float f32x4;

__device__ inline f32x4 mfma16(bf16x8 a, bf16x8 b, f32x4 c) {
    return __builtin_amdgcn_mfma_f32_16x16x32_bf16(a, b, c, 0, 0, 0);
}

__device__ inline void split8v(const f32x4 v0, const f32x4 v1, bf16x8& h, bf16x8& l) {
    float f[8] = {v0[0], v0[1], v0[2], v0[3], v1[0], v1[1], v1[2], v1[3]};
#pragma unroll
    for (int j = 0; j < 8; ++j) {
        __bf16 hh = (__bf16)f[j];
        h[j] = hh;
        l[j] = (__bf16)(f[j] - (float)hh);
    }
}

// ---------------------------------------------------------------------------
// pack_b: x [16384,64] fp32 row-major  ->  MFMA B-fragment-ordered bf16 hi/lo.
// Packed index: (((kb*4 + t)*64 + lane)*8 + j)
//   holds x[kb*32 + (lane>>4)*8 + j][t*16 + (lane&15)]
// ---------------------------------------------------------------------------
__global__ __launch_bounds__(256) void pack_b(const float* __restrict__ x,
                                              __bf16* __restrict__ hi,
                                              __bf16* __restrict__ lo) {
    __shared__ float tile[32 * 64];
    const int kb = blockIdx.x;  // 0..511, 32 k-rows each
    const f32x4* src = (const f32x4*)(x + (size_t)kb * 32 * 64);
    f32x4* dst = (f32x4*)tile;
    dst[threadIdx.x] = src[threadIdx.x];
    dst[threadIdx.x + 256] = src[threadIdx.x + 256];
    __syncthreads();
    const int t = threadIdx.x >> 6;    // n-tile 0..3
    const int l = threadIdx.x & 63;    // consumer lane
    const int col = (t << 4) + (l & 15);
    const int krow = (l >> 4) * 8;
    bf16x8 h8, l8;
#pragma unroll
    for (int j = 0; j < 8; ++j) {
        float v = tile[(krow + j) * 64 + col];
        __bf16 hh = (__bf16)v;
        h8[j] = hh;
        l8[j] = (__bf16)(v - (float)hh);
    }
    const size_t base = (((size_t)kb * 4 + t) * 64 + l) * 8;
    *(bf16x8*)(hi + base) = h8;
    *(bf16x8*)(lo + base) = l8;
}

// ---------------------------------------------------------------------------
// gemm_partial: partial[ks] = adj[:, ks-chunk] @ x[ks-chunk, :]
// r13's barrier-free template pushed to B:A = 1:2 (measured curve: 2:1 ->
// 4.4 TB/s, 1:1 -> 5.1; extrapolate 1:2 -> ~5.6). G=8: each wave owns 128
// rows (8 x 16-row groups); per 32-k step: 16 A-instr + 8 B-instr + 96 MFMA.
// A loaded in two 4-group half-batches so batch 2 flies under batch 1's
// MFMAs. Block = 4 waves x 128 rows = 512 rows; grid = 32 rt x 8 ks = 256
// = 1 block/CU (BW-bound regime tolerates 1 wave/SIMD: per-step serial cost
// ~640ns << 2.6us HBM budget per 64KB/CU step; in-flight A 64KB >> 9KB
// BW*latency; r6/r7 occupancy nulls). launch_bounds(256,1): ~235 VGPR, no
// spill. No barriers anywhere in the K-loop (r14 lesson).
// adj loads plain (L1 merges half-line pairs; nt double-fetched, r3/r4).
// Partial stores nt (no reuse, keep L2 for B).
// ---------------------------------------------------------------------------
__global__ __launch_bounds__(256, 1) void gemm_partial(const float* __restrict__ adj,
                                                       const __bf16* __restrict__ Bhi,
                                                       const __bf16* __restrict__ Blo,
                                                       float* __restrict__ partial) {
    const int lane = threadIdx.x & 63;
    const int wv = threadIdx.x >> 6;   // wave -> 128-row group
    const int rt = blockIdx.x & 31;    // row-tile 0..31 (512 rows each)
    const int ks = blockIdx.x >> 5;    // k-split 0..7
    const int rbase = rt * 512 + wv * 128;
    const int rq = lane & 15;          // A row within 16-row group
    const int kq = lane >> 4;          // k-quarter 0..3

    f32x4 acc[8][4];
#pragma unroll
    for (int g = 0; g < 8; ++g)
#pragma unroll
        for (int t = 0; t < 4; ++t) acc[g][t] = f32x4{0.f, 0.f, 0.f, 0.f};

    const float* ap = adj + (size_t)(rbase + rq) * NROWS + ks * KCH + kq * 8;
    const int kk0 = ks * KCH;

    for (int kk = 0; kk < KCH; kk += 32) {
        // A half-batch 1: groups 0-3 (8 instrs, oldest in queue)
        f32x4 av0[4][2];
#pragma unroll
        for (int g = 0; g < 4; ++g) {
            const f32x4* a = (const f32x4*)(ap + (size_t)(g * 16) * NROWS + kk);
            av0[g][0] = a[0];
            av0[g][1] = a[1];
        }
        // B fragments (L2/L1-resident packed bf16), 8 x 16B, wave-shared
        const size_t bb = ((size_t)((kk0 + kk) >> 5) * 4) * 512 + (size_t)lane * 8;
        bf16x8 bh[4], bl[4];
#pragma unroll
        for (int t = 0; t < 4; ++t) {
            bh[t] = *(const bf16x8*)(Bhi + bb + (size_t)t * 512);
            bl[t] = *(const bf16x8*)(Blo + bb + (size_t)t * 512);
        }
        // A half-batch 2: groups 4-7 (youngest; in flight during MFMAs below)
        f32x4 av1[4][2];
#pragma unroll
        for (int g = 0; g < 4; ++g) {
            const f32x4* a = (const f32x4*)(ap + (size_t)((g + 4) * 16) * NROWS + kk);
            av1[g][0] = a[0];
            av1[g][1] = a[1];
        }
        // consume groups 0-3 (only waits on av0+B; av1 still flying)
#pragma unroll
        for (int g = 0; g < 4; ++g) {
            bf16x8 ah, al;
            split8v(av0[g][0], av0[g][1], ah, al);
#pragma unroll
            for (int t = 0; t < 4; ++t) {
                acc[g][t] = mfma16(ah, bh[t], acc[g][t]);
                acc[g][t] = mfma16(ah, bl[t], acc[g][t]);
                acc[g][t] = mfma16(al, bh[t], acc[g][t]);
            }
        }
        // consume groups 4-7
#pragma unroll
        for (int g = 0; g < 4; ++g) {
            bf16x8 ah, al;
            split8v(av1[g][0], av1[g][1], ah, al);
#pragma unroll
            for (int t = 0; t < 4; ++t) {
                acc[g + 4][t] = mfma16(ah, bh[t], acc[g + 4][t]);
                acc[g + 4][t] = mfma16(ah, bl[t], acc[g + 4][t]);
                acc[g + 4][t] = mfma16(al, bh[t], acc[g + 4][t]);
            }
        }
    }

    // C/D layout: col = lane&15, row = (lane>>4)*4 + reg   [m89-verified]
    float* pp = partial + (size_t)ks * (NROWS * HID) + (size_t)rbase * HID;
#pragma unroll
    for (int g = 0; g < 8; ++g)
#pragma unroll
        for (int t = 0; t < 4; ++t)
#pragma unroll
            for (int r = 0; r < 4; ++r)
                __builtin_nontemporal_store(acc[g][t][r],
                    pp + (g * 16 + kq * 4 + r) * HID + t * 16 + rq);
}

// ---------------------------------------------------------------------------
// reduce_dense(+optional fused pack): agg_r = sum_ks partial[ks][r];
// v = tanh([agg_r|x_r] @ W); writes xout, and when hi!=null also emits the
// bf16 hi/lo packed-B form of v for the next hop's gemm (saves the pack_b
// launch + x1 re-read). Block handles rows [blockIdx*32, +32) = pack kb.
// ---------------------------------------------------------------------------
__global__ __launch_bounds__(256) void reduce_dense(const float* __restrict__ partial,
                                                    const float* __restrict__ xin,
                                                    const float* __restrict__ W,
                                                    float* __restrict__ xout,
                                                    __bf16* __restrict__ hi,
                                                    __bf16* __restrict__ lo) {
    __shared__ float wsm[128 * 64];  // 32 KB
    __shared__ float xt[32][64];     // 8 KB: this block's 32 output rows
    const f32x4* wsrc = (const f32x4*)W;
    f32x4* wdst = (f32x4*)wsm;
#pragma unroll
    for (int i = 0; i < 8; ++i) wdst[threadIdx.x + 256 * i] = wsrc[threadIdx.x + 256 * i];
    __syncthreads();

    const int lane = threadIdx.x & 63;
    const int wv = threadIdx.x >> 6;
    const int r0 = blockIdx.x * 32 + wv * 8;
#pragma unroll 2
    for (int i = 0; i < 8; ++i) {
        const int r = r0 + i;
        float av = 0.f;
#pragma unroll
        for (int ks = 0; ks < KSPLIT; ++ks)
            av += partial[(size_t)ks * (NROWS * HID) + (size_t)r * HID + lane];
        const float xv = xin[(size_t)r * HID + lane];
        float z = 0.f;
#pragma unroll
        for (int j = 0; j < 64; ++j) z += __shfl(av, j) * wsm[j * 64 + lane];
#pragma unroll
        for (int j = 0; j < 64; ++j) z += __shfl(xv, j) * wsm[(64 + j) * 64 + lane];
        const float v = tanhf(z);
        xout[(size_t)r * HID + lane] = v;
        xt[wv * 8 + i][lane] = v;
    }

    if (hi != nullptr) {
        __syncthreads();
        const int t = threadIdx.x >> 6;
        const int l = threadIdx.x & 63;
        const int col = (t << 4) + (l & 15);
        const int krow = (l >> 4) * 8;
        bf16x8 h8, l8;
#pragma unroll
        for (int j = 0; j < 8; ++j) {
            float v = xt[krow + j][col];
            __bf16 hh = (__bf16)v;
            h8[j] = hh;
            l8[j] = (__bf16)(v - (float)hh);
        }
        const size_t base = (((size_t)blockIdx.x * 4 + t) * 64 + l) * 8;
        *(bf16x8*)(hi + base) = h8;
        *(bf16x8*)(lo + base) = l8;
    }
}

extern "C" void kernel_launch(void* const* d_in, const int* in_sizes, int n_in,
                              void* d_out, int out_size, void* d_ws, size_t ws_size,
                              hipStream_t stream) {
    const float* x0 = (const float*)d_in[0];   // user_embs [16384,64]
    const float* adj = (const float*)d_in[1];  // adj [16384,16384]
    const float* W = (const float*)d_in[2];    // W [2,128,64]
    float* out = (float*)d_out;

    char* ws = (char*)d_ws;
    __bf16* Bhi = (__bf16*)(ws);                       // 2 MB
    __bf16* Blo = (__bf16*)(ws + (2u << 20));          // 2 MB
    float* partial = (float*)(ws + (4u << 20));        // 32 MB (8 x 4 MB)
    float* x1 = (float*)(ws + (36u << 20));            // 4 MB

    // hop 0
    pack_b<<<512, 256, 0, stream>>>(x0, Bhi, Blo);
    gemm_partial<<<KSPLIT * 32, 256, 0, stream>>>(adj, Bhi, Blo, partial);
    reduce_dense<<<512, 256, 0, stream>>>(partial, x0, W, x1, Bhi, Blo);  // fused pack
    // hop 1
    gemm_partial<<<KSPLIT * 32, 256, 0, stream>>>(adj, Bhi, Blo, partial);
    reduce_dense<<<512, 256, 0, stream>>>(partial, x1, W + 128 * 64, out, nullptr, nullptr);
}